// Round 2
// baseline (255.245 us; speedup 1.0000x reference)
//
#include <hip/hip_runtime.h>
#include <stdint.h>

typedef __attribute__((ext_vector_type(8))) short bf16x8;
typedef __attribute__((ext_vector_type(4))) float f32x4;

__device__ __forceinline__ uint32_t f2bf(float f) {
    uint32_t u = __builtin_bit_cast(uint32_t, f);
    u += 0x7fffu + ((u >> 16) & 1u);   // RNE round to bf16
    return u >> 16;
}
__device__ __forceinline__ uint32_t pack2(float a, float b) {
    return f2bf(a) | (f2bf(b) << 16);
}
__device__ __forceinline__ bf16x8 pack8(float4 a, float4 b) {
    union { uint32_t u[4]; bf16x8 v; } r;
    r.u[0] = pack2(a.x, a.y); r.u[1] = pack2(a.z, a.w);
    r.u[2] = pack2(b.x, b.y); r.u[3] = pack2(b.z, b.w);
    return r.v;
}

// Prep: reciprocal norms 1/max(||row||, eps) for que_embed (Q rows) and para_embed (P rows).
__global__ __launch_bounds__(256) void prep_norms(const float* __restrict__ qe,
                                                  const float* __restrict__ pe,
                                                  float* __restrict__ rq,
                                                  float* __restrict__ rp,
                                                  int Q, int Pn) {
    int gw = (blockIdx.x * 256 + threadIdx.x) >> 6;  // one wave per row
    int lane = threadIdx.x & 63;
    if (gw >= Q + Pn) return;
    const float* src = (gw < Q) ? (qe + (size_t)gw * 128) : (pe + (size_t)(gw - Q) * 128);
    float2 v = *(const float2*)(src + lane * 2);
    float s = v.x * v.x + v.y * v.y;
#pragma unroll
    for (int off = 32; off > 0; off >>= 1) s += __shfl_down(s, off, 64);
    if (lane == 0) {
        float r = 1.0f / fmaxf(sqrtf(s), 1e-8f);
        if (gw < Q) rq[gw] = r; else rp[gw - Q] = r;
    }
}

// Fused, no-LDS, no-barrier: each wave owns a 64x64 output tile.
// Fragments loaded straight from global (inputs are L2/L3-resident: A=2MB, B=8MB),
// converted fp32->bf16 in-register. Waves are fully independent -> store stream
// stays saturated; kernel should ride the HBM write roofline.
__global__ __launch_bounds__(256) void fused_gemm(
        const float* __restrict__ qe, const float* __restrict__ pe,
        const int* __restrict__ qid, const int* __restrict__ pid,
        const float* __restrict__ rq, const float* __restrict__ rp,
        float* __restrict__ oxor, float* __restrict__ ocos, int Pn, int nQt) {
    // Bijective XCD swizzle (nwg % 8 == 0): each XCD owns a contiguous p-range,
    // q-major decomposition -> per-XCD working set = all A (2MB) + 1/8 of B (1MB) < 4MB L2.
    const int nwg = gridDim.x;
    const int chunk = nwg >> 3;
    const int bid = blockIdx.x;
    const int wg = (bid & 7) * chunk + (bid >> 3);
    const int qy = wg % nQt;
    const int px = wg / nQt;
    const int pbase = px * 128;
    const int qbase = qy * 128;

    const int t = threadIdx.x;
    const int lane = t & 63;
    const int w = t >> 6;
    const int wq = (w >> 1) * 64;   // wave's q offset in block tile
    const int wp = (w & 1) * 64;    // wave's p offset in block tile
    const int lr = lane & 15;       // fragment row within a 16-row group
    const int lk = (lane >> 4) * 8; // fragment k offset within a 32-k chunk

    const float* abase = qe + (size_t)(qbase + wq + lr) * 128 + lk;
    const float* bbase = pe + (size_t)(pbase + wp + lr) * 128 + lk;

    f32x4 acc[4][4];
#pragma unroll
    for (int i = 0; i < 4; ++i)
#pragma unroll
        for (int j = 0; j < 4; ++j) acc[i][j] = (f32x4){0.f, 0.f, 0.f, 0.f};

#pragma unroll 1   // keep VGPR pressure bounded; TLP across waves hides latency
    for (int kk = 0; kk < 4; ++kk) {
        bf16x8 af[4], bfr[4];
#pragma unroll
        for (int f = 0; f < 4; ++f) {
            const float* pa = abase + f * (16 * 128) + kk * 32;
            float4 a0 = *(const float4*)pa;
            float4 a1 = *(const float4*)(pa + 4);
            af[f] = pack8(a0, a1);
            const float* pb = bbase + f * (16 * 128) + kk * 32;
            float4 b0 = *(const float4*)pb;
            float4 b1 = *(const float4*)(pb + 4);
            bfr[f] = pack8(b0, b1);
        }
        // D = Bfrag(16p x 32k) . Afrag(32k x 16q): lane holds col q = lane&15,
        // rows p = (lane>>4)*4 + reg -> 4 consecutive p per lane = float4 store.
#pragma unroll
        for (int fq = 0; fq < 4; ++fq)
#pragma unroll
            for (int fp = 0; fp < 4; ++fp)
                acc[fq][fp] = __builtin_amdgcn_mfma_f32_16x16x32_bf16(
                    bfr[fp], af[fq], acc[fq][fp], 0, 0, 0);
    }

    // ---- epilogue: scale + equality, float4 stores along P ----
    const int prg = (lane >> 4) * 4;
#pragma unroll
    for (int fq = 0; fq < 4; ++fq) {
        const int qg = qbase + wq + fq * 16 + lr;
        const float rqv = rq[qg];
        const int qv = qid[qg];
        const size_t qrow = (size_t)qg;
#pragma unroll
        for (int fp = 0; fp < 4; ++fp) {
            const int pg = pbase + wp + fp * 16 + prg;
            const float4 rpv = *(const float4*)(rp + pg);
            const int4  pv  = *(const int4*)(pid + pg);
            const f32x4 a = acc[fq][fp];
            const size_t off = qrow * (size_t)Pn + (size_t)pg;
            float4 c4 = { a[0] * rqv * rpv.x, a[1] * rqv * rpv.y,
                          a[2] * rqv * rpv.z, a[3] * rqv * rpv.w };
            float4 x4 = { qv == pv.x ? 1.f : 0.f, qv == pv.y ? 1.f : 0.f,
                          qv == pv.z ? 1.f : 0.f, qv == pv.w ? 1.f : 0.f };
            *(float4*)(ocos + off) = c4;
            *(float4*)(oxor + off) = x4;
        }
    }
}

extern "C" void kernel_launch(void* const* d_in, const int* in_sizes, int n_in,
                              void* d_out, int out_size, void* d_ws, size_t ws_size,
                              hipStream_t stream) {
    const int*   qid = (const int*)d_in[0];
    const int*   pid = (const int*)d_in[1];
    const float* qe  = (const float*)d_in[2];
    const float* pe  = (const float*)d_in[3];
    const int Q  = in_sizes[0];   // 4096
    const int Pn = in_sizes[1];   // 16384

    float* rq = (float*)d_ws;
    float* rp = rq + Q;

    float* oxor = (float*)d_out;
    float* ocos = oxor + (size_t)Q * (size_t)Pn;

    int waves = Q + Pn;
    prep_norms<<<(waves + 3) / 4, 256, 0, stream>>>(qe, pe, rq, rp, Q, Pn);

    const int nQt = Q / 128;
    const int nPt = Pn / 128;
    fused_gemm<<<nQt * nPt, 256, 0, stream>>>(qe, pe, qid, pid, rq, rp, oxor, ocos, Pn, nQt);
}

// Round 3
// 218.053 us; speedup vs baseline: 1.1706x; 1.1706x over previous
//
#include <hip/hip_runtime.h>
#include <stdint.h>

typedef __attribute__((ext_vector_type(8))) short bf16x8;
typedef __attribute__((ext_vector_type(4))) float f32x4;

__device__ __forceinline__ uint32_t f2bf(float f) {
    uint32_t u = __builtin_bit_cast(uint32_t, f);
    u += 0x7fffu + ((u >> 16) & 1u);   // RNE round to bf16
    return u >> 16;
}
__device__ __forceinline__ uint32_t pack2(float a, float b) {
    return f2bf(a) | (f2bf(b) << 16);
}

// Prep 1: reciprocal norms 1/max(||row||, eps).
__global__ __launch_bounds__(256) void prep_norms(const float* __restrict__ qe,
                                                  const float* __restrict__ pe,
                                                  float* __restrict__ rq,
                                                  float* __restrict__ rp,
                                                  int Q, int Pn) {
    int gw = (blockIdx.x * 256 + threadIdx.x) >> 6;  // one wave per row
    int lane = threadIdx.x & 63;
    if (gw >= Q + Pn) return;
    const float* src = (gw < Q) ? (qe + (size_t)gw * 128) : (pe + (size_t)(gw - Q) * 128);
    float2 v = *(const float2*)(src + lane * 2);
    float s = v.x * v.x + v.y * v.y;
#pragma unroll
    for (int off = 32; off > 0; off >>= 1) s += __shfl_down(s, off, 64);
    if (lane == 0) {
        float r = 1.0f / fmaxf(sqrtf(s), 1e-8f);
        if (gw < Q) rq[gw] = r; else rp[gw - Q] = r;
    }
}

// Prep 2: fp32 [rows][128] -> bf16 in MFMA-fragment order.
// Fragment unit (g = 16-row group, c = 32-wide k chunk): 64 lanes x 16B,
// lane holds row g*16+(lane&15), k = c*32+(lane>>4)*8 .. +7.
// Flat halfword offset = ((g*4+c)*64 + lane)*8  -> a wave's fragment load in the
// GEMM is 64 contiguous 16B chunks = one fully-coalesced 1KB transaction.
__global__ __launch_bounds__(256) void conv_frag(const float* __restrict__ src,
                                                 unsigned short* __restrict__ dst,
                                                 int ngroups) {
    int t = blockIdx.x * 256 + threadIdx.x;   // one thread per 8 outputs
    if (t >= ngroups * 256) return;
    int g = t >> 8, rem = t & 255;
    int c = rem >> 6, lane = rem & 63;
    int row = g * 16 + (lane & 15);
    int col = c * 32 + ((lane >> 4) << 3);
    const float* s = src + (size_t)row * 128 + col;
    float4 a0 = *(const float4*)s;
    float4 a1 = *(const float4*)(s + 4);
    uint4 pk = { pack2(a0.x, a0.y), pack2(a0.z, a0.w),
                 pack2(a1.x, a1.y), pack2(a1.z, a1.w) };
    *(uint4*)(dst + (size_t)t * 8) = pk;
}

// Main: no LDS, no barriers. Each wave owns a 64x64 tile; fragments are single
// coalesced dwordx4 loads from the pre-packed bf16 arrays (L2-resident).
__global__ __launch_bounds__(256, 4) void fused_gemm(
        const unsigned short* __restrict__ Qf, const unsigned short* __restrict__ Pf,
        const int* __restrict__ qid, const int* __restrict__ pid,
        const float* __restrict__ rq, const float* __restrict__ rp,
        float* __restrict__ oxor, float* __restrict__ ocos, int Pn, int nQt) {
    // Bijective XCD swizzle (nwg % 8 == 0), q-major: per-XCD working set =
    // all of Qf (1MB) + 1/8 of Pf (0.5MB) < 4MB L2.
    const int nwg = gridDim.x;
    const int chunk = nwg >> 3;
    const int bid = blockIdx.x;
    const int wg = (bid & 7) * chunk + (bid >> 3);
    const int qy = wg % nQt;
    const int px = wg / nQt;
    const int pbase = px * 128;
    const int qbase = qy * 128;

    const int t = threadIdx.x;
    const int lane = t & 63;
    const int w = t >> 6;
    const int wq = (w >> 1) * 64;   // wave's q offset in block tile
    const int wp = (w & 1) * 64;    // wave's p offset in block tile

    // fragment (f, kk) lives at base + (f*4 + kk)*512 halfwords
    const unsigned short* aptr = Qf + (size_t)(((qbase + wq) >> 4) * 4) * 512 + lane * 8;
    const unsigned short* bptr = Pf + (size_t)(((pbase + wp) >> 4) * 4) * 512 + lane * 8;

    f32x4 acc[4][4];
#pragma unroll
    for (int i = 0; i < 4; ++i)
#pragma unroll
        for (int j = 0; j < 4; ++j) acc[i][j] = (f32x4){0.f, 0.f, 0.f, 0.f};

#pragma unroll 1
    for (int kk = 0; kk < 4; ++kk) {
        bf16x8 af[4], bfr[4];
#pragma unroll
        for (int f = 0; f < 4; ++f) {
            af[f]  = *(const bf16x8*)(aptr + (f * 4 + kk) * 512);
            bfr[f] = *(const bf16x8*)(bptr + (f * 4 + kk) * 512);
        }
        // D = Bfrag(16p x 32k) . Afrag(32k x 16q): lane holds col q = lane&15,
        // rows p = (lane>>4)*4 + reg -> 4 consecutive p per lane = float4 store.
#pragma unroll
        for (int fq = 0; fq < 4; ++fq)
#pragma unroll
            for (int fp = 0; fp < 4; ++fp)
                acc[fq][fp] = __builtin_amdgcn_mfma_f32_16x16x32_bf16(
                    bfr[fp], af[fq], acc[fq][fp], 0, 0, 0);
    }

    // ---- epilogue: scale + equality, float4 stores along P ----
    const int lr = lane & 15;
    const int prg = (lane >> 4) * 4;
#pragma unroll
    for (int fq = 0; fq < 4; ++fq) {
        const int qg = qbase + wq + fq * 16 + lr;
        const float rqv = rq[qg];
        const int qv = qid[qg];
        const size_t qrow = (size_t)qg;
#pragma unroll
        for (int fp = 0; fp < 4; ++fp) {
            const int pg = pbase + wp + fp * 16 + prg;
            const float4 rpv = *(const float4*)(rp + pg);
            const int4  pv  = *(const int4*)(pid + pg);
            const f32x4 a = acc[fq][fp];
            const size_t off = qrow * (size_t)Pn + (size_t)pg;
            float4 c4 = { a[0] * rqv * rpv.x, a[1] * rqv * rpv.y,
                          a[2] * rqv * rpv.z, a[3] * rqv * rpv.w };
            float4 x4 = { qv == pv.x ? 1.f : 0.f, qv == pv.y ? 1.f : 0.f,
                          qv == pv.z ? 1.f : 0.f, qv == pv.w ? 1.f : 0.f };
            *(float4*)(ocos + off) = c4;
            *(float4*)(oxor + off) = x4;
        }
    }
}

extern "C" void kernel_launch(void* const* d_in, const int* in_sizes, int n_in,
                              void* d_out, int out_size, void* d_ws, size_t ws_size,
                              hipStream_t stream) {
    const int*   qid = (const int*)d_in[0];
    const int*   pid = (const int*)d_in[1];
    const float* qe  = (const float*)d_in[2];
    const float* pe  = (const float*)d_in[3];
    const int Q  = in_sizes[0];   // 4096
    const int Pn = in_sizes[1];   // 16384

    // ws layout: Qf bf16 (Q*128), Pf bf16 (P*128), rq (Q), rp (P)  ~= 5.3 MB
    unsigned short* Qf = (unsigned short*)d_ws;
    unsigned short* Pf = Qf + (size_t)Q * 128;
    float* rq = (float*)(Pf + (size_t)Pn * 128);
    float* rp = rq + Q;

    float* oxor = (float*)d_out;
    float* ocos = oxor + (size_t)Q * (size_t)Pn;

    const int qgroups = Q / 16, pgroups = Pn / 16;
    conv_frag<<<qgroups, 256, 0, stream>>>(qe, Qf, qgroups);
    conv_frag<<<pgroups, 256, 0, stream>>>(pe, Pf, pgroups);
    prep_norms<<<(Q + Pn + 3) / 4, 256, 0, stream>>>(qe, pe, rq, rp, Q, Pn);

    const int nQt = Q / 128;
    const int nPt = Pn / 128;
    fused_gemm<<<nQt * nPt, 256, 0, stream>>>(Qf, Pf, qid, pid, rq, rp, oxor, ocos, Pn, nQt);
}

// Round 5
// 194.801 us; speedup vs baseline: 1.3103x; 1.1194x over previous
//
#include <hip/hip_runtime.h>
#include <stdint.h>

typedef __attribute__((ext_vector_type(8))) short bf16x8;
typedef __attribute__((ext_vector_type(4))) float f32x4;
typedef __attribute__((ext_vector_type(4))) int   i32x4;

__device__ __forceinline__ uint32_t f2bf(float f) {
    uint32_t u = __builtin_bit_cast(uint32_t, f);
    u += 0x7fffu + ((u >> 16) & 1u);   // RNE round to bf16
    return u >> 16;
}
__device__ __forceinline__ uint32_t pack2(float a, float b) {
    return f2bf(a) | (f2bf(b) << 16);
}

// Prep 1: reciprocal norms 1/max(||row||, eps).
__global__ __launch_bounds__(256) void prep_norms(const float* __restrict__ qe,
                                                  const float* __restrict__ pe,
                                                  float* __restrict__ rq,
                                                  float* __restrict__ rp,
                                                  int Q, int Pn) {
    int gw = (blockIdx.x * 256 + threadIdx.x) >> 6;  // one wave per row
    int lane = threadIdx.x & 63;
    if (gw >= Q + Pn) return;
    const float* src = (gw < Q) ? (qe + (size_t)gw * 128) : (pe + (size_t)(gw - Q) * 128);
    float2 v = *(const float2*)(src + lane * 2);
    float s = v.x * v.x + v.y * v.y;
#pragma unroll
    for (int off = 32; off > 0; off >>= 1) s += __shfl_down(s, off, 64);
    if (lane == 0) {
        float r = 1.0f / fmaxf(sqrtf(s), 1e-8f);
        if (gw < Q) rq[gw] = r; else rp[gw - Q] = r;
    }
}

// Prep 2: fp32 [rows][128] -> bf16 in MFMA-fragment order.
// Fragment unit (g = 16-row group, c = 32-wide k chunk): 64 lanes x 16B,
// lane holds row g*16+(lane&15), k = c*32+(lane>>4)*8 .. +7.
// Flat halfword offset = ((g*4+c)*64 + lane)*8.
__global__ __launch_bounds__(256) void conv_frag(const float* __restrict__ src,
                                                 unsigned short* __restrict__ dst,
                                                 int ngroups) {
    int t = blockIdx.x * 256 + threadIdx.x;   // one thread per 8 outputs
    if (t >= ngroups * 256) return;
    int g = t >> 8, rem = t & 255;
    int c = rem >> 6, lane = rem & 63;
    int row = g * 16 + (lane & 15);
    int col = c * 32 + ((lane >> 4) << 3);
    const float* s = src + (size_t)row * 128 + col;
    float4 a0 = *(const float4*)s;
    float4 a1 = *(const float4*)(s + 4);
    uint4 pk = { pack2(a0.x, a0.y), pack2(a0.z, a0.w),
                 pack2(a1.x, a1.y), pack2(a1.z, a1.w) };
    *(uint4*)(dst + (size_t)t * 8) = pk;
}

// Main kernel: 128q x 128p block tile, 4 waves (2x2 of 64x64).
// B tile staged to LDS via global_load_lds (linear, pre-packed fragment order),
// A fragments resident in VGPRs. ONE barrier. Stores are spread across the
// kernel (per-fq strips) as nontemporal 16B stores.
__global__ __launch_bounds__(256, 3) void fused_gemm(
        const unsigned short* __restrict__ Qf, const unsigned short* __restrict__ Pf,
        const int* __restrict__ qid, const int* __restrict__ pid,
        const float* __restrict__ rq, const float* __restrict__ rp,
        float* __restrict__ oxor, float* __restrict__ ocos, int Pn, int nPt) {
    __shared__ __align__(16) unsigned short Bs[128 * 128];   // 32 KB

    // Bijective XCD chunking; p fastest within a chunk -> consecutive blocks
    // write adjacent 512B segments of the SAME output rows (DRAM page locality),
    // and each XCD streams Pf (4MB) through its own L2 while its Qf slice stays hot.
    const int nwg = gridDim.x;
    const int chunk = nwg >> 3;
    const int bid = blockIdx.x;
    const int wg = (bid & 7) * chunk + (bid >> 3);
    const int qy = wg / nPt;
    const int px = wg % nPt;
    const int pbase = px * 128;
    const int qbase = qy * 128;

    const int t = threadIdx.x;
    const int lane = t & 63;
    const int w = t >> 6;
    const int wq = (w >> 1) * 64;   // wave's q offset in block tile
    const int wp = (w & 1) * 64;    // wave's p offset in block tile

    // ---- stage B tile: one linear 32KB copy from Pf (already fragment-ordered) ----
    {
        const unsigned short* src = Pf + (size_t)pbase * 128;
#pragma unroll
        for (int i = 0; i < 8; ++i) {
            const int c = i * 4 + w;   // 1KB chunk index, wave-uniform
            __builtin_amdgcn_global_load_lds(
                (const uint32_t*)(src + (size_t)c * 512 + lane * 8),
                (uint32_t*)((char*)Bs + c * 1024), 16, 0, 0);
        }
    }

    // ---- A fragments -> registers (16 coalesced 1KB wave loads) ----
    bf16x8 af[4][4];
    {
        const unsigned short* abase = Qf + (size_t)((qbase + wq) >> 4) * 2048 + lane * 8;
#pragma unroll
        for (int fq = 0; fq < 4; ++fq)
#pragma unroll
            for (int kk = 0; kk < 4; ++kk)
                af[fq][kk] = *(const bf16x8*)(abase + (fq * 4 + kk) * 512);
    }

    __syncthreads();   // drains global_load_lds + A loads

    const int lr = lane & 15;
    const int prg = (lane >> 4) * 4;

#pragma unroll
    for (int fq = 0; fq < 4; ++fq) {
        f32x4 acc[4];
#pragma unroll
        for (int fp = 0; fp < 4; ++fp) acc[fp] = (f32x4){0.f, 0.f, 0.f, 0.f};

#pragma unroll
        for (int kk = 0; kk < 4; ++kk) {
#pragma unroll
            for (int fp = 0; fp < 4; ++fp) {
                const bf16x8 bfr = *(const bf16x8*)((const char*)Bs +
                    ((((wp >> 4) + fp) * 4 + kk) << 10) + lane * 16);
                // D = Bfrag(16p x 32k) . Afrag(32k x 16q): lane holds q col = lane&15,
                // p rows = (lane>>4)*4 + reg -> 16B store along P.
                acc[fp] = __builtin_amdgcn_mfma_f32_16x16x32_bf16(
                    bfr, af[fq][kk], acc[fp], 0, 0, 0);
            }
        }

        // ---- store this 16q x 64p strip now (spread the write stream) ----
        const int qg = qbase + wq + fq * 16 + lr;
        const float rqv = rq[qg];
        const int qv = qid[qg];
        const size_t qrow = (size_t)qg;
#pragma unroll
        for (int fp = 0; fp < 4; ++fp) {
            const int pg = pbase + wp + fp * 16 + prg;
            const float4 rpv = *(const float4*)(rp + pg);
            const int4  pv  = *(const int4*)(pid + pg);
            const f32x4 a = acc[fp];
            const size_t off = qrow * (size_t)Pn + (size_t)pg;
            f32x4 c4 = { a[0] * rqv * rpv.x, a[1] * rqv * rpv.y,
                         a[2] * rqv * rpv.z, a[3] * rqv * rpv.w };
            f32x4 x4 = { qv == pv.x ? 1.f : 0.f, qv == pv.y ? 1.f : 0.f,
                         qv == pv.z ? 1.f : 0.f, qv == pv.w ? 1.f : 0.f };
            __builtin_nontemporal_store(c4, (f32x4*)(ocos + off));
            __builtin_nontemporal_store(x4, (f32x4*)(oxor + off));
        }
    }
}

extern "C" void kernel_launch(void* const* d_in, const int* in_sizes, int n_in,
                              void* d_out, int out_size, void* d_ws, size_t ws_size,
                              hipStream_t stream) {
    const int*   qid = (const int*)d_in[0];
    const int*   pid = (const int*)d_in[1];
    const float* qe  = (const float*)d_in[2];
    const float* pe  = (const float*)d_in[3];
    const int Q  = in_sizes[0];   // 4096
    const int Pn = in_sizes[1];   // 16384

    // ws layout: Qf bf16 (Q*128), Pf bf16 (P*128), rq (Q), rp (P)  ~= 5.3 MB
    unsigned short* Qf = (unsigned short*)d_ws;
    unsigned short* Pf = Qf + (size_t)Q * 128;
    float* rq = (float*)(Pf + (size_t)Pn * 128);
    float* rp = rq + Q;

    float* oxor = (float*)d_out;
    float* ocos = oxor + (size_t)Q * (size_t)Pn;

    const int qgroups = Q / 16, pgroups = Pn / 16;
    conv_frag<<<qgroups, 256, 0, stream>>>(qe, Qf, qgroups);
    conv_frag<<<pgroups, 256, 0, stream>>>(pe, Pf, pgroups);
    prep_norms<<<(Q + Pn + 3) / 4, 256, 0, stream>>>(qe, pe, rq, rp, Q, Pn);

    const int nQt = Q / 128;
    const int nPt = Pn / 128;
    fused_gemm<<<nQt * nPt, 256, 0, stream>>>(Qf, Pf, qid, pid, rq, rp, oxor, ocos, Pn, nPt);
}